// Round 11
// baseline (81.475 us; speedup 1.0000x reference)
//
#include <hip/hip_runtime.h>
#include <hip/hip_bf16.h>

typedef float f32x4 __attribute__((ext_vector_type(4)));

namespace {
constexpr int kB = 4;
constexpr int kT = 4096;
constexpr int kC = 8;
constexpr int kTRows = 128;            // t-rows per block band
constexpr int kSPerThread = 4;         // s-cols per thread (f32x4 store)
constexpr int kBlockThreads = 256;
constexpr int kSTile = kBlockThreads * kSPerThread;  // 1024 s-cols
}

__device__ __forceinline__ void softmax8(const float e[kC], float p[kC]) {
    float m = e[0];
#pragma unroll
    for (int i = 1; i < kC; ++i) m = fmaxf(m, e[i]);
    float sum = 0.f;
#pragma unroll
    for (int i = 0; i < kC; ++i) { p[i] = __expf(e[i] - m); sum += p[i]; }
    float inv = __builtin_amdgcn_rcpf(sum);
#pragma unroll
    for (int i = 0; i < kC; ++i) p[i] *= inv;
}

// Fully fused, no workspace: block = 128 t-rows x 1024 s-cols (512 blocks).
// 128 lanes compute p rows -> LDS (1 gather each); every thread computes
// z = -(Cmat softmax(emb[tok_s])) for its 4 s-cols in registers. Redundancy
// across t-bands is 32x (halved vs R9); prologue amortized over 128
// stores/thread. All global gathers issued up front to overlap latency.
__global__ __launch_bounds__(256) void dam_fused(const int* __restrict__ token_ids,
                                                 const float* __restrict__ emb,
                                                 const float* __restrict__ cmat,
                                                 float* __restrict__ out) {
    const int b = blockIdx.z;
    const int t0 = blockIdx.y * kTRows;
    const int s0 = blockIdx.x * kSTile;
    const int tid = threadIdx.x;

    __shared__ f32x4 p_lds[kTRows * 2];   // 128 rows x 8 floats = 4 KB

    // ---- issue all gathers first ----
    f32x4 pe0, pe1;
    if (tid < kTRows) {
        int tokT = token_ids[b * kT + t0 + tid];
        const f32x4* prow = reinterpret_cast<const f32x4*>(emb) + (size_t)tokT * 2;
        pe0 = prow[0];
        pe1 = prow[1];
    }

    const int s = s0 + tid * kSPerThread;
    int4 toks = *reinterpret_cast<const int4*>(&token_ids[b * kT + s]);
    int tokS[kSPerThread] = {toks.x, toks.y, toks.z, toks.w};
    f32x4 se[kSPerThread][2];
#pragma unroll
    for (int j = 0; j < kSPerThread; ++j) {
        const f32x4* srow = reinterpret_cast<const f32x4*>(emb) + (size_t)tokS[j] * 2;
        se[j][0] = srow[0];
        se[j][1] = srow[1];
    }

    // ---- p rows -> LDS ----
    if (tid < kTRows) {
        float e[kC] = {pe0.x, pe0.y, pe0.z, pe0.w, pe1.x, pe1.y, pe1.z, pe1.w};
        float p[kC];
        softmax8(e, p);
        p_lds[tid * 2 + 0] = f32x4{p[0], p[1], p[2], p[3]};
        p_lds[tid * 2 + 1] = f32x4{p[4], p[5], p[6], p[7]};
    }
    __syncthreads();

    // ---- z for my 4 s-cols: z[c] = -sum_d cmat[c][d] * softmax(emb_s)[d] ----
    float z[kSPerThread][kC];
#pragma unroll
    for (int j = 0; j < kSPerThread; ++j) {
        float e[kC] = {se[j][0].x, se[j][0].y, se[j][0].z, se[j][0].w,
                       se[j][1].x, se[j][1].y, se[j][1].z, se[j][1].w};
        float q[kC];
        softmax8(e, q);
#pragma unroll
        for (int c = 0; c < kC; ++c) {
            float acc = 0.f;
#pragma unroll
            for (int d = 0; d < kC; ++d) acc = fmaf(cmat[c * kC + d], q[d], acc);
            z[j][c] = -acc;
        }
    }

    // ---- main loop: 128 rows x 4 cols per thread ----
    float* orow = out + ((size_t)(b * kT + t0)) * kT + s;
#pragma unroll 4
    for (int tt = 0; tt < kTRows; ++tt) {
        f32x4 p0 = p_lds[tt * 2 + 0];
        f32x4 p1 = p_lds[tt * 2 + 1];
        float pr[kC] = {p0.x, p0.y, p0.z, p0.w, p1.x, p1.y, p1.z, p1.w};
        float r[kSPerThread];
#pragma unroll
        for (int j = 0; j < kSPerThread; ++j) {
            float acc = 0.f;   // acc = -compat
#pragma unroll
            for (int i = 0; i < kC; ++i) acc = fmaf(pr[i], z[j][i], acc);
            // 2*sigmoid(-acc)-1 = (1 - e^acc) / (1 + e^acc)
            float ex = __expf(acc);
            r[j] = (1.f - ex) * __builtin_amdgcn_rcpf(1.f + ex);
        }
        f32x4 ov = {r[0], r[1], r[2], r[3]};
        *reinterpret_cast<f32x4*>(orow + (size_t)tt * kT) = ov;
    }
}

extern "C" void kernel_launch(void* const* d_in, const int* in_sizes, int n_in,
                              void* d_out, int out_size, void* d_ws, size_t ws_size,
                              hipStream_t stream) {
    const int* token_ids = (const int*)d_in[0];
    const float* emb     = (const float*)d_in[1];
    const float* cmat    = (const float*)d_in[2];
    float* out = (float*)d_out;

    dim3 grid(kT / kSTile, kT / kTRows, kB);   // (4, 32, 4) = 512 blocks
    dam_fused<<<grid, kBlockThreads, 0, stream>>>(token_ids, emb, cmat, out);
}

// Round 12
// 50.092 us; speedup vs baseline: 1.6265x; 1.6265x over previous
//
#include <hip/hip_runtime.h>
#include <hip/hip_bf16.h>

typedef float f32x4 __attribute__((ext_vector_type(4)));

namespace {
constexpr int kB = 4;
constexpr int kT = 4096;
constexpr int kC = 8;
constexpr int kTRows = 64;             // t-rows per block band (sharp optimum)
constexpr int kSPerThread = 4;         // s-cols per thread (f32x4 store)
constexpr int kBlockThreads = 256;
constexpr int kSTile = kBlockThreads * kSPerThread;  // 1024 s-cols
}

// softmax without max-subtraction: logits are N(0,1); exp safe in fp32.
__device__ __forceinline__ void softmax8_nomax(const float e[kC], float p[kC]) {
    float sum = 0.f;
#pragma unroll
    for (int i = 0; i < kC; ++i) { p[i] = __expf(e[i]); sum += p[i]; }
    float inv = __builtin_amdgcn_rcpf(sum);
#pragma unroll
    for (int i = 0; i < kC; ++i) p[i] *= inv;
}

// Fused, no workspace: block = 64 t-rows x 1024 s-cols (1024 blocks, 4/CU).
// Identity: p_t . (C p_s) = (C^T p_t) . p_s  -> the 8x8 matvec is done ONCE
// per t-row (64/block, in the 64-lane p-phase, stored negated in LDS) instead
// of per s-col (1024/block in R9). s-side prologue is now just softmax8.
__global__ __launch_bounds__(256) void dam_fused(const int* __restrict__ token_ids,
                                                 const float* __restrict__ emb,
                                                 const float* __restrict__ cmat,
                                                 float* __restrict__ out) {
    const int b = blockIdx.z;
    const int t0 = blockIdx.y * kTRows;
    const int s0 = blockIdx.x * kSTile;
    const int tid = threadIdx.x;

    __shared__ f32x4 w_lds[kTRows * 2];   // 64 rows x 8 floats of w_t = -(C^T p_t)

    // ---- issue all gathers first ----
    const int s = s0 + tid * kSPerThread;
    int4 toks = *reinterpret_cast<const int4*>(&token_ids[b * kT + s]);
    int tokS[kSPerThread] = {toks.x, toks.y, toks.z, toks.w};
    f32x4 se[kSPerThread][2];
#pragma unroll
    for (int j = 0; j < kSPerThread; ++j) {
        const f32x4* srow = reinterpret_cast<const f32x4*>(emb) + (size_t)tokS[j] * 2;
        se[j][0] = srow[0];
        se[j][1] = srow[1];
    }

    f32x4 pe0, pe1;
    if (tid < kTRows) {
        int tokT = token_ids[b * kT + t0 + tid];
        const f32x4* prow = reinterpret_cast<const f32x4*>(emb) + (size_t)tokT * 2;
        pe0 = prow[0];
        pe1 = prow[1];
    }

    // ---- p-phase: w_t = -(C^T p_t) -> LDS (64 lanes, one row each) ----
    if (tid < kTRows) {
        float e[kC] = {pe0.x, pe0.y, pe0.z, pe0.w, pe1.x, pe1.y, pe1.z, pe1.w};
        float p[kC];
        softmax8_nomax(e, p);
        float w[kC];
#pragma unroll
        for (int c = 0; c < kC; ++c) {
            float acc = 0.f;
#pragma unroll
            for (int d = 0; d < kC; ++d) acc = fmaf(cmat[d * kC + c], p[d], acc);  // C^T
            w[c] = -acc;
        }
        w_lds[tid * 2 + 0] = f32x4{w[0], w[1], w[2], w[3]};
        w_lds[tid * 2 + 1] = f32x4{w[4], w[5], w[6], w[7]};
    }
    __syncthreads();

    // ---- s-phase: q_s = softmax(emb[tok_s]) only (no matvec) ----
    float q[kSPerThread][kC];
#pragma unroll
    for (int j = 0; j < kSPerThread; ++j) {
        float e[kC] = {se[j][0].x, se[j][0].y, se[j][0].z, se[j][0].w,
                       se[j][1].x, se[j][1].y, se[j][1].z, se[j][1].w};
        softmax8_nomax(e, q[j]);
    }

    // ---- main loop: 64 rows x 4 cols per thread ----
    float* orow = out + ((size_t)(b * kT + t0)) * kT + s;
#pragma unroll 4
    for (int tt = 0; tt < kTRows; ++tt) {
        f32x4 w0 = w_lds[tt * 2 + 0];
        f32x4 w1 = w_lds[tt * 2 + 1];
        float wr[kC] = {w0.x, w0.y, w0.z, w0.w, w1.x, w1.y, w1.z, w1.w};
        float r[kSPerThread];
#pragma unroll
        for (int j = 0; j < kSPerThread; ++j) {
            float acc = 0.f;   // acc = -compat
#pragma unroll
            for (int i = 0; i < kC; ++i) acc = fmaf(wr[i], q[j][i], acc);
            // 2*sigmoid(-acc)-1 = (1 - e^acc) / (1 + e^acc)
            float ex = __expf(acc);
            r[j] = (1.f - ex) * __builtin_amdgcn_rcpf(1.f + ex);
        }
        f32x4 ov = {r[0], r[1], r[2], r[3]};
        *reinterpret_cast<f32x4*>(orow + (size_t)tt * kT) = ov;
    }
}

extern "C" void kernel_launch(void* const* d_in, const int* in_sizes, int n_in,
                              void* d_out, int out_size, void* d_ws, size_t ws_size,
                              hipStream_t stream) {
    const int* token_ids = (const int*)d_in[0];
    const float* emb     = (const float*)d_in[1];
    const float* cmat    = (const float*)d_in[2];
    float* out = (float*)d_out;

    dim3 grid(kT / kSTile, kT / kTRows, kB);   // (4, 64, 4) = 1024 blocks
    dam_fused<<<grid, kBlockThreads, 0, stream>>>(token_ids, emb, cmat, out);
}

// Round 13
// 49.658 us; speedup vs baseline: 1.6407x; 1.0087x over previous
//
#include <hip/hip_runtime.h>
#include <hip/hip_bf16.h>

typedef float f32x4 __attribute__((ext_vector_type(4)));

namespace {
constexpr int kB = 4;
constexpr int kT = 4096;
constexpr int kC = 8;
constexpr int kTRows = 64;             // t-rows per block band (sharp optimum)
constexpr int kSPerThread = 4;         // s-cols per thread (f32x4 store)
constexpr int kBlockThreads = 256;
constexpr int kWaves = kBlockThreads / 64;
constexpr int kSTile = kBlockThreads * kSPerThread;  // 1024 s-cols
}

// softmax without max-subtraction: logits are N(0,1); exp safe in fp32.
__device__ __forceinline__ void softmax8_nomax(const float e[kC], float p[kC]) {
    float sum = 0.f;
#pragma unroll
    for (int i = 0; i < kC; ++i) { p[i] = __expf(e[i]); sum += p[i]; }
    float inv = __builtin_amdgcn_rcpf(sum);
#pragma unroll
    for (int i = 0; i < kC; ++i) p[i] *= inv;
}

// Fused, BARRIER-FREE: block = 64 t-rows x 1024 s-cols (1024 blocks, 4/CU).
// Each WAVE keeps a private copy of the w-table (w_t = -(C^T p_t), one row
// per lane) in its own LDS region; wave-internal LDS RAW needs only the
// wave's lgkmcnt scoreboard -> no __syncthreads, waves run free (no convoy
// on the slowest wave's gather chain).
__global__ __launch_bounds__(256) void dam_fused(const int* __restrict__ token_ids,
                                                 const float* __restrict__ emb,
                                                 const float* __restrict__ cmat,
                                                 float* __restrict__ out) {
    const int b = blockIdx.z;
    const int t0 = blockIdx.y * kTRows;
    const int s0 = blockIdx.x * kSTile;
    const int tid = threadIdx.x;
    const int wid = tid >> 6;
    const int lane = tid & 63;

    __shared__ f32x4 w_lds[kWaves][kTRows * 2];   // per-wave copies, 8 KB

    // ---- issue all gathers up front; t-row first (longest chain) ----
    int tokT = token_ids[b * kT + t0 + lane];
    const f32x4* prow = reinterpret_cast<const f32x4*>(emb) + (size_t)tokT * 2;
    f32x4 pe0 = prow[0], pe1 = prow[1];

    const int s = s0 + tid * kSPerThread;
    int4 toks = *reinterpret_cast<const int4*>(&token_ids[b * kT + s]);
    int tokS[kSPerThread] = {toks.x, toks.y, toks.z, toks.w};
    f32x4 se[kSPerThread][2];
#pragma unroll
    for (int j = 0; j < kSPerThread; ++j) {
        const f32x4* srow = reinterpret_cast<const f32x4*>(emb) + (size_t)tokS[j] * 2;
        se[j][0] = srow[0];
        se[j][1] = srow[1];
    }

    // ---- p-phase (every lane, own wave's copy): w = -(C^T p) -> LDS ----
    {
        float e[kC] = {pe0.x, pe0.y, pe0.z, pe0.w, pe1.x, pe1.y, pe1.z, pe1.w};
        float p[kC];
        softmax8_nomax(e, p);
        float w[kC];
#pragma unroll
        for (int c = 0; c < kC; ++c) {
            float acc = 0.f;
#pragma unroll
            for (int d = 0; d < kC; ++d) acc = fmaf(cmat[d * kC + c], p[d], acc);  // C^T
            w[c] = -acc;
        }
        w_lds[wid][lane * 2 + 0] = f32x4{w[0], w[1], w[2], w[3]};
        w_lds[wid][lane * 2 + 1] = f32x4{w[4], w[5], w[6], w[7]};
    }
    // NO __syncthreads: only same-wave lanes read this region; the wave's own
    // lgkmcnt ordering guarantees the writes are visible to its ds_reads.

    // ---- s-phase: q_s = softmax(emb[tok_s]) ----
    float q[kSPerThread][kC];
#pragma unroll
    for (int j = 0; j < kSPerThread; ++j) {
        float e[kC] = {se[j][0].x, se[j][0].y, se[j][0].z, se[j][0].w,
                       se[j][1].x, se[j][1].y, se[j][1].z, se[j][1].w};
        softmax8_nomax(e, q[j]);
    }

    // ---- main loop: 64 rows x 4 cols per thread ----
    float* orow = out + ((size_t)(b * kT + t0)) * kT + s;
#pragma unroll 4
    for (int tt = 0; tt < kTRows; ++tt) {
        f32x4 w0 = w_lds[wid][tt * 2 + 0];
        f32x4 w1 = w_lds[wid][tt * 2 + 1];
        float wr[kC] = {w0.x, w0.y, w0.z, w0.w, w1.x, w1.y, w1.z, w1.w};
        float r[kSPerThread];
#pragma unroll
        for (int j = 0; j < kSPerThread; ++j) {
            float acc = 0.f;   // acc = -compat
#pragma unroll
            for (int i = 0; i < kC; ++i) acc = fmaf(wr[i], q[j][i], acc);
            // 2*sigmoid(-acc)-1 = (1 - e^acc) / (1 + e^acc)
            float ex = __expf(acc);
            r[j] = (1.f - ex) * __builtin_amdgcn_rcpf(1.f + ex);
        }
        f32x4 ov = {r[0], r[1], r[2], r[3]};
        *reinterpret_cast<f32x4*>(orow + (size_t)tt * kT) = ov;
    }
}

extern "C" void kernel_launch(void* const* d_in, const int* in_sizes, int n_in,
                              void* d_out, int out_size, void* d_ws, size_t ws_size,
                              hipStream_t stream) {
    const int* token_ids = (const int*)d_in[0];
    const float* emb     = (const float*)d_in[1];
    const float* cmat    = (const float*)d_in[2];
    float* out = (float*)d_out;

    dim3 grid(kT / kSTile, kT / kTRows, kB);   // (4, 64, 4) = 1024 blocks
    dam_fused<<<grid, kBlockThreads, 0, stream>>>(token_ids, emb, cmat, out);
}